// Round 2
// baseline (680.509 us; speedup 1.0000x reference)
//
#include <hip/hip_runtime.h>

#define Bn 32
#define Nn 24564
#define NPAD 32768
#define MAXB 200

typedef unsigned long long u64;

// -------- accurate-enough double exp (rel err ~6e-15) --------
__device__ inline double fast_exp_d(double x) {
  const double LOG2E = 1.4426950408889634074;
  const double LN2   = 0.69314718055994530942;
  double t = x * LOG2E;
  double fi = floor(t + 0.5);
  double f = (t - fi) * LN2;   // |f_ln2| <= 0.3466
  double p = 2.505210838544172e-8;           // 1/11!
  p = p * f + 2.755731922398589e-7;          // 1/10!
  p = p * f + 2.7557319223985893e-6;         // 1/9!
  p = p * f + 2.48015873015873e-5;           // 1/8!
  p = p * f + 1.984126984126984e-4;          // 1/7!
  p = p * f + 1.3888888888888889e-3;         // 1/6!
  p = p * f + 8.333333333333333e-3;          // 1/5!
  p = p * f + 4.1666666666666664e-2;         // 1/4!
  p = p * f + 1.6666666666666666e-1;         // 1/3!
  p = p * f + 0.5;
  p = p * f + 1.0;
  p = p * f + 1.0;
  long long e = (long long)fi;
  double sc = __longlong_as_double((e + 1023LL) << 52);
  return p * sc;
}

__device__ inline double clip01(double v) {
  return v < 0.0 ? 0.0 : (v > 1.0 ? 1.0 : v);
}

// ============================================================
// K1: per-anchor softmax-max score (f64), argmax class, box decode (f64)
// ============================================================
__global__ __launch_bounds__(128) void k_score(const float* __restrict__ logits,
                                               const float* __restrict__ anchors,
                                               double* __restrict__ boxesd,
                                               int* __restrict__ clsd,
                                               u64* __restrict__ keys) {
  __shared__ float lds[128 * 85];
  const int tid = threadIdx.x;
  const int bid = blockIdx.x;
  const int b = bid >> 8;              // 256 chunks of 128 anchors -> 32768 slots
  const int n0 = (bid & 255) << 7;
  int cnt = Nn - n0;
  cnt = cnt < 0 ? 0 : (cnt > 128 ? 128 : cnt);
  if (cnt > 0) {
    const int nf4 = (cnt * 85) >> 2;   // cnt*85 divisible by 4 here (cnt=128 or 116)
    const float4* src = reinterpret_cast<const float4*>(logits + ((size_t)b * Nn + n0) * 85);
    float4* dst = reinterpret_cast<float4*>(lds);
    for (int i = tid; i < nf4; i += 128) dst[i] = src[i];
  }
  __syncthreads();
  const int n = n0 + tid;
  u64 K = ~0ULL;
  if (tid < cnt) {
    const float* row = lds + tid * 85;
    float maxl = row[4];
    int argc = 0;
    #pragma unroll 1
    for (int c = 1; c < 81; ++c) {
      float v = row[4 + c];
      if (v > maxl) { maxl = v; argc = c; }
    }
    double sum = 0.0;
    #pragma unroll 1
    for (int c = 0; c < 81; ++c) sum += fast_exp_d((double)row[4 + c] - (double)maxl);
    double score = 1.0 / sum;

    float4 a4 = reinterpret_cast<const float4*>(anchors)[n];
    double ax1 = a4.x, ay1 = a4.y, ax2 = a4.z, ay2 = a4.w;
    double cx = (ax2 + ax1) * 0.5, cy = (ay2 + ay1) * 0.5;
    double ww = ax2 - ax1, hh = ay2 - ay1;
    double ctrx = (double)row[0] * ww + cx;
    double ctry = (double)row[1] * hh + cy;
    double szx = fast_exp_d((double)row[2]) * ww;
    double szy = fast_exp_d((double)row[3]) * hh;
    double x1 = clip01(ctrx - szx * 0.5);
    double y1 = clip01(ctry - szy * 0.5);
    double x2 = clip01(ctrx + szx * 0.5);
    double y2 = clip01(ctry + szy * 0.5);
    double* bp = boxesd + (size_t)(b * Nn + n) * 4;
    bp[0] = x1; bp[1] = y1; bp[2] = x2; bp[3] = y2;
    clsd[b * Nn + n] = argc;

    if (argc != 0 && score >= 0.01) {
      u64 sb = (u64)__double_as_longlong(score);      // score in [0.01, 1] -> exp 1016..1023
      u64 e4 = (sb >> 52) - 1015ULL;                  // 1..8
      u64 mant45 = (sb & ((1ULL << 52) - 1)) >> 7;    // top 45 mantissa bits
      u64 key49 = (e4 << 45) | mant45;
      u64 flip = (~key49) & ((1ULL << 49) - 1);
      K = (flip << 15) | (u64)n;                      // n < 32768
    }
  }
  keys[(size_t)b * NPAD + n] = K;
}

// ============================================================
// K2: per-image bitonic sort of keys[b][0..32767] ascending (u64)
// ============================================================
__device__ inline void gstage(u64* data, int k, int j, int tid) {
  for (int i = tid; i < 16384; i += 1024) {
    int l = ((i & ~(j - 1)) << 1) | (i & (j - 1));
    int r = l | j;
    bool up = ((l & k) == 0);
    u64 a = data[l], bb = data[r];
    if ((a > bb) == up) { data[l] = bb; data[r] = a; }
  }
  __syncthreads();
}

__device__ inline void cpass(u64* data, u64* s, int gb, int k, int tid) {
  for (int i = tid; i < 4096; i += 1024) s[i] = data[gb + i];
  __syncthreads();
  for (int j = 2048; j >= 1; j >>= 1) {
    for (int p = tid; p < 2048; p += 1024) {
      int l = ((p & ~(j - 1)) << 1) | (p & (j - 1));
      int r = l | j;
      bool up = (((gb + l) & k) == 0);
      u64 a = s[l], bb = s[r];
      if ((a > bb) == up) { s[l] = bb; s[r] = a; }
    }
    __syncthreads();
  }
  for (int i = tid; i < 4096; i += 1024) data[gb + i] = s[i];
  __syncthreads();
}

__device__ inline void csort(u64* data, u64* s, int gb, int tid) {
  for (int i = tid; i < 4096; i += 1024) s[i] = data[gb + i];
  __syncthreads();
  for (int k = 2; k <= 4096; k <<= 1) {
    for (int j = k >> 1; j >= 1; j >>= 1) {
      for (int p = tid; p < 2048; p += 1024) {
        int l = ((p & ~(j - 1)) << 1) | (p & (j - 1));
        int r = l | j;
        bool up = (((gb + l) & k) == 0);
        u64 a = s[l], bb = s[r];
        if ((a > bb) == up) { s[l] = bb; s[r] = a; }
      }
      __syncthreads();
    }
  }
  for (int i = tid; i < 4096; i += 1024) data[gb + i] = s[i];
  __syncthreads();
}

__global__ __launch_bounds__(1024) void k_sort(u64* __restrict__ keys) {
  __shared__ u64 s[4096];
  const int tid = threadIdx.x;
  u64* data = keys + (size_t)blockIdx.x * NPAD;
  // full sort of chunks 0..5 (chunks 6,7 are all-pad = all-equal keys: trivially sorted)
  for (int c = 0; c < 6; ++c) csort(data, s, c * 4096, tid);
  // round k=8192
  gstage(data, 8192, 4096, tid);
  for (int c = 0; c < 8; ++c) cpass(data, s, c * 4096, 8192, tid);
  // round k=16384
  gstage(data, 16384, 8192, tid);
  gstage(data, 16384, 4096, tid);
  for (int c = 0; c < 8; ++c) cpass(data, s, c * 4096, 16384, tid);
  // round k=32768 (final ascending)
  gstage(data, 32768, 16384, tid);
  gstage(data, 32768, 8192, tid);
  gstage(data, 32768, 4096, tid);
  for (int c = 0; c < 8; ++c) cpass(data, s, c * 4096, 32768, tid);
}

// ============================================================
// K3: wave-0-per-image greedy NMS over sorted candidates + output write
// NOTE: harness reads the ENTIRE out buffer as float32 -> classes/num
// must be written as float VALUES, not int bit patterns.
// ============================================================
__global__ __launch_bounds__(256) void k_nms(const double* __restrict__ boxesd,
                                             const int* __restrict__ clsd,
                                             const u64* __restrict__ keys,
                                             float* __restrict__ out) {
  __shared__ double selBox[MAXB][4];
  __shared__ double selArea[MAXB];
  __shared__ float selScore[MAXB];
  __shared__ int selIdx[MAXB];
  __shared__ int sS;
  const int b = blockIdx.x;
  const int tid = threadIdx.x;
  const double THR = 0.45;

  if (tid < 64) {
    const int lane = tid;
    int S = 0;
    int pos = 0;
    const u64* kb = keys + (size_t)b * NPAD;
    while (S < MAXB && pos < NPAD) {
      u64 K = kb[pos + lane];
      bool valid = (K != ~0ULL);
      if (!__any(valid)) break;   // sorted: nothing valid later either
      int idx = (int)(K & 0x7FFF);
      double bx1 = 0, by1 = 0, bx2 = 0, by2 = 0, area = 0;
      float sc = 0.f;
      if (valid) {
        const double* bp = boxesd + (size_t)(b * Nn + idx) * 4;
        bx1 = bp[0]; by1 = bp[1]; bx2 = bp[2]; by2 = bp[3];
        area = (bx2 - bx1) * (by2 - by1);
        u64 key49 = (~(K >> 15)) & ((1ULL << 49) - 1);
        u64 e = (key49 >> 45) + 1015ULL;
        u64 mant = (key49 & ((1ULL << 45) - 1)) << 7;
        sc = (float)__longlong_as_double((long long)((e << 52) | mant));
      }
      bool alive = valid;
      // phase 1: vs committed selections
      for (int k = 0; k < S; ++k) {
        double ltx = fmax(selBox[k][0], bx1), lty = fmax(selBox[k][1], by1);
        double rbx = fmin(selBox[k][2], bx2), rby = fmin(selBox[k][3], by2);
        double w = rbx - ltx; w = w < 0 ? 0 : w;
        double h = rby - lty; h = h < 0 ? 0 : h;
        double inter = w * h;
        double denom = selArea[k] + area - inter + 1e-9;
        if (inter > THR * denom) alive = false;
        if ((k & 15) == 15 && !__any(alive)) break;
      }
      // phase 2: sequential acceptance within batch (score-descending = lane order)
      u64 m = __ballot(alive);
      while (m != 0 && S < MAXB) {
        int j = __ffsll((unsigned long long)m) - 1;
        double jx1 = __shfl(bx1, j), jy1 = __shfl(by1, j);
        double jx2 = __shfl(bx2, j), jy2 = __shfl(by2, j);
        double jar = __shfl(area, j);
        float jsc = __shfl(sc, j);
        int jidx = __shfl(idx, j);
        if (lane == 0) {
          selBox[S][0] = jx1; selBox[S][1] = jy1; selBox[S][2] = jx2; selBox[S][3] = jy2;
          selArea[S] = jar; selScore[S] = jsc; selIdx[S] = jidx;
        }
        S++;
        m &= ~(1ULL << j);
        double ltx = fmax(jx1, bx1), lty = fmax(jy1, by1);
        double rbx = fmin(jx2, bx2), rby = fmin(jy2, by2);
        double w = rbx - ltx; w = w < 0 ? 0 : w;
        double h = rby - lty; h = h < 0 ? 0 : h;
        double inter = w * h;
        double denom = jar + area - inter + 1e-9;
        bool sup = (inter > THR * denom);
        m &= ~__ballot(sup);
      }
      pos += 64;
    }
    if (lane == 0) sS = S;
  }
  __syncthreads();
  const int S = sS;
  float* det_boxes = out;                                    // [B,200,4] f32
  float* det_classes = out + Bn * MAXB * 4;                  // [B,200]  f32 VALUES
  float* det_scores = out + Bn * MAXB * 4 + Bn * MAXB;       // [B,200]  f32
  float* det_num = out + Bn * MAXB * 4 + 2 * Bn * MAXB;      // [B]      f32 VALUES
  for (int k = tid; k < MAXB; k += 256) {
    int o = b * MAXB + k;
    if (k < S) {
      det_boxes[o * 4 + 0] = (float)selBox[k][0];
      det_boxes[o * 4 + 1] = (float)selBox[k][1];
      det_boxes[o * 4 + 2] = (float)selBox[k][2];
      det_boxes[o * 4 + 3] = (float)selBox[k][3];
      det_classes[o] = (float)clsd[b * Nn + selIdx[k]];
      det_scores[o] = selScore[k];
    } else {
      det_boxes[o * 4 + 0] = 0.f; det_boxes[o * 4 + 1] = 0.f;
      det_boxes[o * 4 + 2] = 0.f; det_boxes[o * 4 + 3] = 0.f;
      det_classes[o] = 0.f;
      det_scores[o] = 0.f;
    }
  }
  if (tid == 0) det_num[b] = (float)S;
}

// ============================================================
extern "C" void kernel_launch(void* const* d_in, const int* in_sizes, int n_in,
                              void* d_out, int out_size, void* d_ws, size_t ws_size,
                              hipStream_t stream) {
  const float* logits = (const float*)d_in[0];
  const float* anchors = (const float*)d_in[1];
  float* out = (float*)d_out;
  char* ws = (char*)d_ws;

  // ws layout: boxes f64 [B*N*4] | cls i32 [B*N] | keys u64 [B*NPAD]  (~36.7 MB)
  double* boxesd = (double*)ws;
  size_t off = (size_t)Bn * Nn * 4 * sizeof(double);
  int* clsd = (int*)(ws + off);
  off += (size_t)Bn * Nn * sizeof(int);
  u64* keys = (u64*)(ws + off);

  k_score<<<dim3(Bn * 256), dim3(128), 0, stream>>>(logits, anchors, boxesd, clsd, keys);
  k_sort<<<dim3(Bn), dim3(1024), 0, stream>>>(keys);
  k_nms<<<dim3(Bn), dim3(256), 0, stream>>>(boxesd, clsd, keys, out);
}

// Round 3
// 408.047 us; speedup vs baseline: 1.6677x; 1.6677x over previous
//
#include <hip/hip_runtime.h>

#define Bn 32
#define Nn 24564
#define MAXB 200
#define KSEL 8192
#define NBIN 4096

typedef unsigned long long u64;

// -------- accurate double exp (rel err ~6e-15) --------
__device__ inline double fast_exp_d(double x) {
  const double LOG2E = 1.4426950408889634074;
  const double LN2   = 0.69314718055994530942;
  double t = x * LOG2E;
  double fi = floor(t + 0.5);
  double f = (t - fi) * LN2;   // |f| <= 0.3466
  double p = 2.505210838544172e-8;
  p = p * f + 2.755731922398589e-7;
  p = p * f + 2.7557319223985893e-6;
  p = p * f + 2.48015873015873e-5;
  p = p * f + 1.984126984126984e-4;
  p = p * f + 1.3888888888888889e-3;
  p = p * f + 8.333333333333333e-3;
  p = p * f + 4.1666666666666664e-2;
  p = p * f + 1.6666666666666666e-1;
  p = p * f + 0.5;
  p = p * f + 1.0;
  p = p * f + 1.0;
  long long e = (long long)fi;
  double sc = __longlong_as_double((e + 1023LL) << 52);
  return p * sc;
}

__device__ inline double clip01(double v) {
  return v < 0.0 ? 0.0 : (v > 1.0 ? 1.0 : v);
}

// ============================================================
// K1: 4 lanes per anchor: softmax-max score (f64), argmax, box decode,
// 64-bit sort key, global histogram of key top-12 bits.
// ============================================================
__global__ __launch_bounds__(512) void k_score(const float* __restrict__ logits,
                                               const float* __restrict__ anchors,
                                               double* __restrict__ boxesd,
                                               int* __restrict__ clsd,
                                               u64* __restrict__ keys,
                                               int* __restrict__ hist) {
  __shared__ float lds[128 * 85];
  const int tid = threadIdx.x;
  const int bid = blockIdx.x;
  const int b = bid / 192;
  const int n0 = (bid % 192) << 7;
  int cnt = Nn - n0;
  cnt = cnt > 128 ? 128 : cnt;      // 128 or 116
  const int nf4 = (cnt * 85) >> 2;  // divisible by 4 for cnt=128/116
  const float4* src = reinterpret_cast<const float4*>(logits + ((size_t)b * Nn + n0) * 85);
  float4* dst = reinterpret_cast<float4*>(lds);
  for (int i = tid; i < nf4; i += 512) dst[i] = src[i];
  __syncthreads();

  const int g = tid >> 2;      // anchor within chunk
  const int s = tid & 3;       // lane within group
  if (g < cnt) {
    const int n = n0 + g;
    const float* row = lds + g * 85;
    // partial max/argmax over classes c = s, s+4, ...
    float mx = -1e30f; int ai = 1000;
    for (int c = s; c < 81; c += 4) {
      float v = row[4 + c];
      if (v > mx) { mx = v; ai = c; }
    }
    // combine within 4-lane group (tie -> smaller index)
    #pragma unroll
    for (int d = 1; d <= 2; d <<= 1) {
      float om = __shfl_xor(mx, d);
      int oi = __shfl_xor(ai, d);
      if (om > mx || (om == mx && oi < ai)) { mx = om; ai = oi; }
    }
    // partial f64 exp-sum
    double sum = 0.0;
    for (int c = s; c < 81; c += 4) sum += fast_exp_d((double)row[4 + c] - (double)mx);
    sum += __shfl_xor(sum, 1);
    sum += __shfl_xor(sum, 2);

    if (s == 0) {
      double score = 1.0 / sum;
      float4 a4 = reinterpret_cast<const float4*>(anchors)[n];
      double ax1 = a4.x, ay1 = a4.y, ax2 = a4.z, ay2 = a4.w;
      double cx = (ax2 + ax1) * 0.5, cy = (ay2 + ay1) * 0.5;
      double ww = ax2 - ax1, hh = ay2 - ay1;
      double ctrx = (double)row[0] * ww + cx;
      double ctry = (double)row[1] * hh + cy;
      double szx = fast_exp_d((double)row[2]) * ww;
      double szy = fast_exp_d((double)row[3]) * hh;
      double x1 = clip01(ctrx - szx * 0.5);
      double y1 = clip01(ctry - szy * 0.5);
      double x2 = clip01(ctrx + szx * 0.5);
      double y2 = clip01(ctry + szy * 0.5);
      double* bp = boxesd + (size_t)(b * Nn + n) * 4;
      bp[0] = x1; bp[1] = y1; bp[2] = x2; bp[3] = y2;
      clsd[b * Nn + n] = ai;

      u64 K = ~0ULL;
      if (ai != 0 && score >= 0.01) {
        u64 sb = (u64)__double_as_longlong(score);   // exp field 1016..1023
        u64 e4 = (sb >> 52) - 1015ULL;               // 1..8
        u64 mant45 = (sb & ((1ULL << 52) - 1)) >> 7;
        u64 key49 = (e4 << 45) | mant45;
        u64 flip = (~key49) & ((1ULL << 49) - 1);
        K = (flip << 15) | (u64)n;                   // ascending = score desc, idx asc
        atomicAdd(&hist[b * NBIN + (int)(K >> 52)], 1);
      }
      keys[(size_t)b * Nn + n] = K;
    }
  }
}

// ============================================================
// K2 (per image, 1024 threads): cutoff-bin select -> compact top<=8192
// keys into LDS -> bitonic sort in LDS -> greedy NMS -> write outputs.
// ============================================================
__global__ __launch_bounds__(1024) void k_select(const u64* __restrict__ keys,
                                                 const double* __restrict__ boxesd,
                                                 const int* __restrict__ clsd,
                                                 const int* __restrict__ hist,
                                                 float* __restrict__ out) {
  __shared__ u64 sel[KSEL];           // 64 KB
  __shared__ int histL[NBIN];         // 16 KB
  __shared__ int part[1024];          // 4 KB
  __shared__ int goff[64];
  __shared__ int sC, sCnt, sS;
  __shared__ double selBox[MAXB][4];
  __shared__ double selArea[MAXB];
  __shared__ float selScore[MAXB];
  __shared__ int selIdx[MAXB];

  const int b = blockIdx.x;
  const int tid = threadIdx.x;

  for (int i = tid; i < NBIN; i += 1024) histL[i] = hist[b * NBIN + i];
  for (int i = tid; i < KSEL; i += 1024) sel[i] = ~0ULL;
  if (tid == 0) { sC = -1; sCnt = 0; }
  __syncthreads();

  // --- find cutoff bin C = largest bin with inclusive cumsum <= KSEL ---
  int psum = 0;
  #pragma unroll
  for (int q = 0; q < 4; ++q) psum += histL[tid * 4 + q];
  part[tid] = psum;
  __syncthreads();
  if (tid < 64) {
    int gs = 0;
    #pragma unroll
    for (int q = 0; q < 16; ++q) gs += part[tid * 16 + q];
    int run = gs;
    for (int d = 1; d < 64; d <<= 1) {
      int v = __shfl_up(run, d);
      if (tid >= d) run += v;
    }
    goff[tid] = run - gs;   // exclusive prefix of 16-groups
  }
  __syncthreads();
  int off = goff[tid >> 4];
  for (int q = (tid >> 4) << 4; q < tid; ++q) off += part[q];
  int run = off, localC = -1;
  #pragma unroll
  for (int q = 0; q < 4; ++q) {
    run += histL[tid * 4 + q];
    if (run <= KSEL) localC = tid * 4 + q;
  }
  if (localC >= 0) atomicMax(&sC, localC);
  __syncthreads();
  const int C = sC;

  // --- compact keys with bin <= C into LDS (order irrelevant; sorted next) ---
  const u64* kb = keys + (size_t)b * Nn;
  for (int i = tid; i < Nn; i += 1024) {
    u64 K = kb[i];
    if ((int)(K >> 52) <= C) {
      int p = atomicAdd(&sCnt, 1);
      sel[p] = K;
    }
  }
  __syncthreads();

  // --- bitonic sort of KSEL u64 in LDS, ascending ---
  for (int k = 2; k <= KSEL; k <<= 1) {
    for (int j = k >> 1; j >= 1; j >>= 1) {
      for (int p = tid; p < (KSEL / 2); p += 1024) {
        int l = ((p & ~(j - 1)) << 1) | (p & (j - 1));
        int r = l | j;
        bool up = ((l & k) == 0);
        u64 a = sel[l], bb = sel[r];
        if ((a > bb) == up) { sel[l] = bb; sel[r] = a; }
      }
      __syncthreads();
    }
  }

  // --- greedy NMS by wave 0 ---
  if (tid < 64) {
    const int lane = tid;
    const double THR = 0.45;
    int S = 0, pos = 0;
    while (S < MAXB && pos < KSEL) {
      u64 K = sel[pos + lane];
      bool valid = (K != ~0ULL);
      if (!__any(valid)) break;
      int idx = (int)(K & 0x7FFF);
      double bx1 = 0, by1 = 0, bx2 = 0, by2 = 0, area = 0;
      float sc = 0.f;
      if (valid) {
        const double* bp = boxesd + (size_t)(b * Nn + idx) * 4;
        bx1 = bp[0]; by1 = bp[1]; bx2 = bp[2]; by2 = bp[3];
        area = (bx2 - bx1) * (by2 - by1);
        u64 key49 = (~(K >> 15)) & ((1ULL << 49) - 1);
        u64 e = (key49 >> 45) + 1015ULL;
        u64 mant = (key49 & ((1ULL << 45) - 1)) << 7;
        sc = (float)__longlong_as_double((long long)((e << 52) | mant));
      }
      bool alive = valid;
      for (int k = 0; k < S; ++k) {
        double ltx = fmax(selBox[k][0], bx1), lty = fmax(selBox[k][1], by1);
        double rbx = fmin(selBox[k][2], bx2), rby = fmin(selBox[k][3], by2);
        double w = rbx - ltx; w = w < 0 ? 0 : w;
        double h = rby - lty; h = h < 0 ? 0 : h;
        double inter = w * h;
        double denom = selArea[k] + area - inter + 1e-9;
        if (inter > THR * denom) alive = false;
        if ((k & 15) == 15 && !__any(alive)) break;
      }
      u64 m = __ballot(alive);
      while (m != 0 && S < MAXB) {
        int j = __ffsll((unsigned long long)m) - 1;
        double jx1 = __shfl(bx1, j), jy1 = __shfl(by1, j);
        double jx2 = __shfl(bx2, j), jy2 = __shfl(by2, j);
        double jar = __shfl(area, j);
        float jsc = __shfl(sc, j);
        int jidx = __shfl(idx, j);
        if (lane == 0) {
          selBox[S][0] = jx1; selBox[S][1] = jy1; selBox[S][2] = jx2; selBox[S][3] = jy2;
          selArea[S] = jar; selScore[S] = jsc; selIdx[S] = jidx;
        }
        S++;
        m &= ~(1ULL << j);
        double ltx = fmax(jx1, bx1), lty = fmax(jy1, by1);
        double rbx = fmin(jx2, bx2), rby = fmin(jy2, by2);
        double w = rbx - ltx; w = w < 0 ? 0 : w;
        double h = rby - lty; h = h < 0 ? 0 : h;
        double inter = w * h;
        double denom = jar + area - inter + 1e-9;
        m &= ~__ballot(inter > THR * denom);
      }
      pos += 64;
    }
    if (lane == 0) sS = S;
  }
  __syncthreads();

  // --- outputs (harness reads whole buffer as f32: classes/num as VALUES) ---
  const int S = sS;
  float* det_boxes = out;
  float* det_classes = out + Bn * MAXB * 4;
  float* det_scores = out + Bn * MAXB * 4 + Bn * MAXB;
  float* det_num = out + Bn * MAXB * 4 + 2 * Bn * MAXB;
  for (int k = tid; k < MAXB; k += 1024) {
    int o = b * MAXB + k;
    if (k < S) {
      det_boxes[o * 4 + 0] = (float)selBox[k][0];
      det_boxes[o * 4 + 1] = (float)selBox[k][1];
      det_boxes[o * 4 + 2] = (float)selBox[k][2];
      det_boxes[o * 4 + 3] = (float)selBox[k][3];
      det_classes[o] = (float)clsd[b * Nn + selIdx[k]];
      det_scores[o] = selScore[k];
    } else {
      det_boxes[o * 4 + 0] = 0.f; det_boxes[o * 4 + 1] = 0.f;
      det_boxes[o * 4 + 2] = 0.f; det_boxes[o * 4 + 3] = 0.f;
      det_classes[o] = 0.f;
      det_scores[o] = 0.f;
    }
  }
  if (tid == 0) det_num[b] = (float)S;
}

// ============================================================
extern "C" void kernel_launch(void* const* d_in, const int* in_sizes, int n_in,
                              void* d_out, int out_size, void* d_ws, size_t ws_size,
                              hipStream_t stream) {
  const float* logits = (const float*)d_in[0];
  const float* anchors = (const float*)d_in[1];
  float* out = (float*)d_out;
  char* ws = (char*)d_ws;

  // ws: boxes f64 [B*N*4] | cls i32 [B*N] | keys u64 [B*N] | hist i32 [B*4096]
  double* boxesd = (double*)ws;
  size_t off = (size_t)Bn * Nn * 4 * sizeof(double);
  int* clsd = (int*)(ws + off);
  off += (size_t)Bn * Nn * sizeof(int);
  u64* keys = (u64*)(ws + off);
  off += (size_t)Bn * Nn * sizeof(u64);
  int* hist = (int*)(ws + off);

  hipMemsetAsync(hist, 0, (size_t)Bn * NBIN * sizeof(int), stream);
  k_score<<<dim3(Bn * 192), dim3(512), 0, stream>>>(logits, anchors, boxesd, clsd, keys, hist);
  k_select<<<dim3(Bn), dim3(1024), 0, stream>>>(keys, boxesd, clsd, hist, out);
}